// Round 3
// baseline (1254.318 us; speedup 1.0000x reference)
//
#include <hip/hip_runtime.h>
#include <cstdint>
#include <cstddef>

// Problem constants (R,1,C) x, t, (K,C) A, (T,) bar_alpha
#define R_DIM 4096
#define K_DIM 16384
#define C_DIM 512
#define SPLITS 4                 // split over the 16384 k-dimension
#define BM 64                    // rows per workgroup
#define BK 128                   // k-tile
#define KRANGE (K_DIM / SPLITS)  // 4096
#define NTILES (KRANGE / BK)     // 32
#define GTILES (K_DIM / BK)      // 128 global tiles

typedef unsigned short us8 __attribute__((ext_vector_type(8)));
typedef float f32x4 __attribute__((ext_vector_type(4)));
typedef __bf16 bfv8 __attribute__((ext_vector_type(8)));

#define MFMA16(a, b, c) __builtin_amdgcn_mfma_f32_16x16x32_bf16((a), (b), (c), 0, 0, 0)
#define BC(v) __builtin_bit_cast(bfv8, (v))

__device__ __forceinline__ unsigned short f2bf(float v) {
    union { float f; unsigned u; } x; x.f = v;
    unsigned r = x.u + 0x7fffu + ((x.u >> 16) & 1u);  // RNE
    return (unsigned short)(r >> 16);
}
__device__ __forceinline__ float bf2f(unsigned short b) {
    union { unsigned u; float f; } x; x.u = ((unsigned)b) << 16;
    return x.f;
}

__device__ __forceinline__ void gload16(const char* g, char* l) {
    __builtin_amdgcn_global_load_lds(
        (const __attribute__((address_space(1))) void*)g,
        (__attribute__((address_space(3))) void*)l, 16, 0, 0);
}

// ---------------- workspace layout (bytes) ----------------
#define OFF_IMGA ((size_t)0)          // [GTILES][8][32768]  32 MB   [128k][64c] images
#define OFF_IMGC ((size_t)33554432)   // [GTILES][8][32768]  32 MB   [64c][128k] images
#define OFF_XH   ((size_t)67108864)   // [R][C] bf16 hi    4 MB
#define OFF_XL   ((size_t)71303168)   // [R][C] bf16 lo    4 MB
#define OFF_ASQ  ((size_t)75497472)   // [K] f32          64 KB
#define OFF_ROWP ((size_t)75563008)   // [R] float4       64 KB  {sa, 0.5*sa*sa, inv*log2e, inv}
#define OFF_PO   ((size_t)75628544)   // [R][SPLITS][C] f32  32 MB
#define OFF_PM   ((size_t)109182976)  // [R][SPLITS] f32  64 KB
#define OFF_PL   ((size_t)109248512)  // [R][SPLITS] f32  64 KB
#define WS_NEED  ((size_t)109314048)

// ---------------- LDS layout (bytes) ----------------
#define SM_BUF0 0        // staging buffer 0: 32 KB (hi 16K, lo 16K)
#define SM_BUF1 32768    // staging buffer 1: 32 KB
#define SM_U    65536    // u hi [64m][128k] bf16 swizzled  16 KB
#define SM_U2   81920    // u lo                            16 KB
#define SM_MX   98304    // float[4][64] tile-max exchange  1 KB
#define SM_SM   99328    // float[4][64] tile-sum exchange  1 KB
#define SM_TOT  100352

// ======================= prep kernels =======================

__global__ void k_rows(const int* __restrict__ t, const float* __restrict__ bar_alpha,
                       float4* __restrict__ rowp) {
    int r = blockIdx.x * 256 + threadIdx.x;
    if (r >= R_DIM) return;
    float ba = bar_alpha[t[r]];
    float sa = sqrtf(ba);
    float inv = 1.0f / (1.0f - ba);
    rowp[r] = make_float4(sa, 0.5f * sa * sa, inv * 1.4426950408889634f, inv);
}

__global__ void k_splitx(const float* __restrict__ x, us8* __restrict__ xh, us8* __restrict__ xl) {
    int i = blockIdx.x * 256 + threadIdx.x;   // group of 8 elements
    if (i >= R_DIM * C_DIM / 8) return;
    const float4* x4 = (const float4*)x + (size_t)i * 2;
    float v[8];
    float4 a = x4[0], b = x4[1];
    v[0]=a.x; v[1]=a.y; v[2]=a.z; v[3]=a.w; v[4]=b.x; v[5]=b.y; v[6]=b.z; v[7]=b.w;
    us8 h, l;
#pragma unroll
    for (int j = 0; j < 8; ++j) {
        unsigned short hb = f2bf(v[j]);
        h[j] = hb;
        l[j] = f2bf(v[j] - bf2f(hb));
    }
    xh[i] = h; xl[i] = l;
}

// Phase-A chunk images: block = (gt, j). pos = kl*128 + ((cb*16) ^ ((kl&7)<<4))
__global__ __launch_bounds__(256) void k_imgA(const float* __restrict__ A, char* __restrict__ img) {
    int gt = blockIdx.x >> 3, j = blockIdx.x & 7;
    char* base = img + (size_t)blockIdx.x * 32768;
    int t = threadIdx.x;
#pragma unroll
    for (int it = 0; it < 4; ++it) {
        int p = t + it * 256;
        int kl = p >> 3, cb = p & 7;
        const float* src = A + (size_t)(gt * 128 + kl) * C_DIM + j * 64 + cb * 8;
        us8 h, l;
#pragma unroll
        for (int q = 0; q < 8; ++q) {
            float v = src[q];
            unsigned short hb = f2bf(v);
            h[q] = hb; l[q] = f2bf(v - bf2f(hb));
        }
        int pos = kl * 128 + ((cb * 16) ^ ((kl & 7) << 4));
        *(us8*)(base + pos) = h;
        *(us8*)(base + 16384 + pos) = l;
    }
}

// Phase-C chunk images (transposed): pos = cl*256 + ((kb*16) ^ ((cl&7)<<4))
__global__ __launch_bounds__(256) void k_imgC(const float* __restrict__ A, char* __restrict__ img) {
    int gt = blockIdx.x >> 3, j = blockIdx.x & 7;
    char* base = img + (size_t)blockIdx.x * 32768;
    int t = threadIdx.x;
#pragma unroll
    for (int it = 0; it < 4; ++it) {
        int p = t + it * 256;
        int cl = p & 63, kb = p >> 6;
        us8 h, l;
#pragma unroll
        for (int q = 0; q < 8; ++q) {
            float v = A[(size_t)(gt * 128 + kb * 8 + q) * C_DIM + j * 64 + cl];
            unsigned short hb = f2bf(v);
            h[q] = hb; l[q] = f2bf(v - bf2f(hb));
        }
        int pos = cl * 256 + ((kb * 16) ^ ((cl & 7) << 4));
        *(us8*)(base + pos) = h;
        *(us8*)(base + 16384 + pos) = l;
    }
}

__global__ void k_asq(const float* __restrict__ A, float* __restrict__ Asq) {
    int wid = threadIdx.x >> 6, lane = threadIdx.x & 63;
    int k = blockIdx.x * 4 + wid;
    const float4* a4 = (const float4*)(A + (size_t)k * C_DIM);
    float s = 0.f;
#pragma unroll
    for (int j = 0; j < 2; ++j) {
        float4 v = a4[lane * 2 + j];
        s += v.x * v.x + v.y * v.y + v.z * v.z + v.w * v.w;
    }
#pragma unroll
    for (int off = 32; off; off >>= 1) s += __shfl_xor(s, off);
    if (lane == 0) Asq[k] = s;
}

// ======================= fused flash-style kernel =======================
// grid = 256 (= #CUs, 1 block/CU). XCD-pinned split: split=(b&7)>>1 so each
// XCD's 32 blocks stream the SAME img sequence in lockstep -> L2 reuse.
// 8 waves = 2 m-groups (wm: 32 rows, M_rep=2) x 4 n-groups (wn).
// LDS B-frag dup = 2 (was 4): halves LDS read traffic per chunk.
__global__ __launch_bounds__(512, 2) void k_fused(
    const char* __restrict__ imgA, const char* __restrict__ imgC,
    const unsigned short* __restrict__ xh, const unsigned short* __restrict__ xl,
    const float* __restrict__ Asq, const float4* __restrict__ rowp,
    float* __restrict__ pO, float* __restrict__ pM, float* __restrict__ pL)
{
    extern __shared__ char smem[];
    const int tid = threadIdx.x;
    const int lane = tid & 63, wid = tid >> 6;
    const int wm = wid >> 2, wn = wid & 3;
    const int l15 = lane & 15, l4 = lane >> 4;
    const int b = blockIdx.x;
    const int split = (b & 7) >> 1;                 // XCD pair -> split
    const int rb = (((b >> 3) << 1) | (b & 1)) * BM;

    // per-lane params for the 8 D-layout rows: m = wm*32 + mf*16 + l4*4 + q
    float sa[2][4], hb[2][4], ce[2][4];
#pragma unroll
    for (int mf = 0; mf < 2; ++mf)
#pragma unroll
        for (int q = 0; q < 4; ++q) {
            float4 p = rowp[rb + wm * 32 + mf * 16 + l4 * 4 + q];
            sa[mf][q] = p.x; hb[mf][q] = p.y; ce[mf][q] = p.z;
        }
    float Mr[2][4], Lr[2][4];
#pragma unroll
    for (int mf = 0; mf < 2; ++mf)
#pragma unroll
        for (int q = 0; q < 4; ++q) { Mr[mf][q] = -1e30f; Lr[mf][q] = 0.f; }
    f32x4 of[8][2];   // [c-chunk j][mf]
#pragma unroll
    for (int a = 0; a < 8; ++a)
#pragma unroll
        for (int m = 0; m < 2; ++m) of[a][m] = (f32x4){0.f, 0.f, 0.f, 0.f};

    const int stg = tid * 16;

    // prologue: stage A(tile 0, chunk 0) into BUF0
    {
        const char* s = imgA + (size_t)(split * NTILES) * 8 * 32768 + stg;
        char* d = smem + SM_BUF0 + stg;
#pragma unroll
        for (int i = 0; i < 4; ++i) gload16(s + i * 8192, d + i * 8192);
    }
    __syncthreads();
    int cur = 0;

    for (int kt = 0; kt < NTILES; ++kt) {
        const int gt = split * NTILES + kt;
        const int kbase = gt * BK;
        f32x4 sf[2][2];   // [mf][kf]
#pragma unroll
        for (int m = 0; m < 2; ++m)
#pragma unroll
            for (int k = 0; k < 2; ++k) sf[m][k] = (f32x4){0.f, 0.f, 0.f, 0.f};

        // ---------- Phase A: S[64m][128k] over c, 8 chunks of 64 ----------
#pragma unroll
        for (int j = 0; j < 8; ++j) {
            // stage next chunk (A j+1, or C 0 when j==7) into buf^1
            {
                const char* s = (j < 7) ? imgA + ((size_t)gt * 8 + j + 1) * 32768
                                        : imgC + ((size_t)gt * 8 + 0) * 32768;
                char* d = smem + (cur ? SM_BUF0 : SM_BUF1) + stg;
#pragma unroll
                for (int i = 0; i < 4; ++i) gload16(s + stg + i * 8192, d + i * 8192);
            }
            // x fragments for this chunk (L1/L2-resident; runs on a different pipe)
            us8 xhf[2][2], xlf[2][2];
#pragma unroll
            for (int mf = 0; mf < 2; ++mf)
#pragma unroll
                for (int cs = 0; cs < 2; ++cs) {
                    int off = (rb + wm * 32 + mf * 16 + l15) * C_DIM + j * 64 + cs * 32 + l4 * 8;
                    xhf[mf][cs] = *(const us8*)(xh + off);
                    xlf[mf][cs] = *(const us8*)(xl + off);
                }
            // MFMA on current buffer
            const char* B = smem + (cur ? SM_BUF1 : SM_BUF0);
#pragma unroll
            for (int cs = 0; cs < 2; ++cs) {
#pragma unroll
                for (int kf = 0; kf < 2; ++kf) {
                    int row = wn * 32 + kf * 16 + l15;         // k-index in tile
                    int byte = row * 128 + ((cs * 64 + l4 * 16) ^ ((row & 7) << 4));
                    bfv8 qh = *(const bfv8*)(B + byte);
                    bfv8 ql = *(const bfv8*)(B + 16384 + byte);
#pragma unroll
                    for (int mf = 0; mf < 2; ++mf) {
                        sf[mf][kf] = MFMA16(BC(xhf[mf][cs]), qh, sf[mf][kf]);
                        sf[mf][kf] = MFMA16(BC(xhf[mf][cs]), ql, sf[mf][kf]);
                        sf[mf][kf] = MFMA16(BC(xlf[mf][cs]), qh, sf[mf][kf]);
                    }
                }
            }
            __syncthreads();
            cur ^= 1;
        }

        // ---------- Phase B: online softmax ----------
        // lane holds: m = wm*32+mf*16+l4*4+q, k = wn*32+kf*16+l15
        float g[2][2][4];
#pragma unroll
        for (int kf = 0; kf < 2; ++kf) {
            float asq = Asq[kbase + wn * 32 + kf * 16 + l15];
#pragma unroll
            for (int mf = 0; mf < 2; ++mf)
#pragma unroll
                for (int q = 0; q < 4; ++q)
                    g[mf][kf][q] = sa[mf][q] * sf[mf][kf][q] - hb[mf][q] * asq;
        }
        float tmax[2][4];
#pragma unroll
        for (int mf = 0; mf < 2; ++mf)
#pragma unroll
            for (int q = 0; q < 4; ++q)
                tmax[mf][q] = fmaxf(g[mf][0][q], g[mf][1][q]);
#pragma unroll
        for (int off = 1; off < 16; off <<= 1)
#pragma unroll
            for (int mf = 0; mf < 2; ++mf)
#pragma unroll
                for (int q = 0; q < 4; ++q)
                    tmax[mf][q] = fmaxf(tmax[mf][q], __shfl_xor(tmax[mf][q], off));
        float* smax = (float*)(smem + SM_MX);
        if (l15 == 0) {
#pragma unroll
            for (int mf = 0; mf < 2; ++mf)
#pragma unroll
                for (int q = 0; q < 4; ++q)
                    smax[wn * 64 + wm * 32 + mf * 16 + l4 * 4 + q] = tmax[mf][q];
        }
        __syncthreads();
        float Mn[2][4], al[2][4];
#pragma unroll
        for (int mf = 0; mf < 2; ++mf)
#pragma unroll
            for (int q = 0; q < 4; ++q) {
                int m = wm * 32 + mf * 16 + l4 * 4 + q;
                float tm = fmaxf(fmaxf(smax[m], smax[64 + m]),
                                 fmaxf(smax[128 + m], smax[192 + m]));
                Mn[mf][q] = fmaxf(Mr[mf][q], tm);
                al[mf][q] = exp2f((Mr[mf][q] - Mn[mf][q]) * ce[mf][q]);
            }
        float u[2][2][4], tsum[2][4];
#pragma unroll
        for (int mf = 0; mf < 2; ++mf)
#pragma unroll
            for (int q = 0; q < 4; ++q) tsum[mf][q] = 0.f;
#pragma unroll
        for (int mf = 0; mf < 2; ++mf)
#pragma unroll
            for (int kf = 0; kf < 2; ++kf)
#pragma unroll
                for (int q = 0; q < 4; ++q) {
                    u[mf][kf][q] = exp2f((g[mf][kf][q] - Mn[mf][q]) * ce[mf][q]);
                    tsum[mf][q] += u[mf][kf][q];
                }
#pragma unroll
        for (int off = 1; off < 16; off <<= 1)
#pragma unroll
            for (int mf = 0; mf < 2; ++mf)
#pragma unroll
                for (int q = 0; q < 4; ++q) tsum[mf][q] += __shfl_xor(tsum[mf][q], off);
        float* ssum = (float*)(smem + SM_SM);
        if (l15 == 0) {
#pragma unroll
            for (int mf = 0; mf < 2; ++mf)
#pragma unroll
                for (int q = 0; q < 4; ++q)
                    ssum[wn * 64 + wm * 32 + mf * 16 + l4 * 4 + q] = tsum[mf][q];
        }
        // write u (bf16 hi/lo) to LDS for GEMM2 A-operand
#pragma unroll
        for (int mf = 0; mf < 2; ++mf)
#pragma unroll
            for (int kf = 0; kf < 2; ++kf)
#pragma unroll
                for (int q = 0; q < 4; ++q) {
                    int m_loc = wm * 32 + mf * 16 + l4 * 4 + q;
                    int k_loc = wn * 32 + kf * 16 + l15;
                    int byte = (m_loc * 256 + k_loc * 2) ^ ((m_loc & 7) << 4);
                    unsigned short uh = f2bf(u[mf][kf][q]);
                    *(unsigned short*)(smem + SM_U + byte) = uh;
                    *(unsigned short*)(smem + SM_U2 + byte) = f2bf(u[mf][kf][q] - bf2f(uh));
                }
        __syncthreads();
#pragma unroll
        for (int mf = 0; mf < 2; ++mf)
#pragma unroll
            for (int q = 0; q < 4; ++q) {
                int m = wm * 32 + mf * 16 + l4 * 4 + q;
                float s4 = (ssum[m] + ssum[64 + m]) + (ssum[128 + m] + ssum[192 + m]);
                Lr[mf][q] = Lr[mf][q] * al[mf][q] + s4;
                Mr[mf][q] = Mn[mf][q];
            }
#pragma unroll
        for (int a = 0; a < 8; ++a)
#pragma unroll
            for (int mf = 0; mf < 2; ++mf)
#pragma unroll
                for (int q = 0; q < 4; ++q) of[a][mf][q] *= al[mf][q];

        // ---------- Phase C: O[64m][512c] += u * A_tile, 8 chunks of 64 c ----------
        us8 uhf[2][4], ulf[2][4];
#pragma unroll
        for (int mf = 0; mf < 2; ++mf)
#pragma unroll
            for (int ks = 0; ks < 4; ++ks) {
                int m_loc = wm * 32 + mf * 16 + l15;
                int byte = (m_loc * 256 + ks * 64 + l4 * 16) ^ ((m_loc & 7) << 4);
                uhf[mf][ks] = *(const us8*)(smem + SM_U + byte);
                ulf[mf][ks] = *(const us8*)(smem + SM_U2 + byte);
            }
#pragma unroll
        for (int j = 0; j < 8; ++j) {
            // stage next chunk (C j+1, or next tile's A 0)
            if (j < 7) {
                const char* s = imgC + ((size_t)gt * 8 + j + 1) * 32768;
                char* d = smem + (cur ? SM_BUF0 : SM_BUF1) + stg;
#pragma unroll
                for (int i = 0; i < 4; ++i) gload16(s + stg + i * 8192, d + i * 8192);
            } else if (kt < NTILES - 1) {
                const char* s = imgA + ((size_t)(gt + 1) * 8 + 0) * 32768;
                char* d = smem + (cur ? SM_BUF0 : SM_BUF1) + stg;
#pragma unroll
                for (int i = 0; i < 4; ++i) gload16(s + stg + i * 8192, d + i * 8192);
            }
            const char* B = smem + (cur ? SM_BUF1 : SM_BUF0);
#pragma unroll
            for (int ks = 0; ks < 4; ++ks) {
                int cl = wn * 16 + l15;                        // c-row in chunk
                int byte = cl * 256 + ((ks * 64 + l4 * 16) ^ ((cl & 7) << 4));
                bfv8 qh = *(const bfv8*)(B + byte);
                bfv8 ql = *(const bfv8*)(B + 16384 + byte);
#pragma unroll
                for (int mf = 0; mf < 2; ++mf) {
                    of[j][mf] = MFMA16(BC(uhf[mf][ks]), qh, of[j][mf]);
                    of[j][mf] = MFMA16(BC(uhf[mf][ks]), ql, of[j][mf]);
                    of[j][mf] = MFMA16(BC(ulf[mf][ks]), qh, of[j][mf]);
                }
            }
            __syncthreads();
            cur ^= 1;
        }
    }

    // ---------- write split partials ----------
#pragma unroll
    for (int j = 0; j < 8; ++j)
#pragma unroll
        for (int mf = 0; mf < 2; ++mf)
#pragma unroll
            for (int q = 0; q < 4; ++q) {
                int gm = rb + wm * 32 + mf * 16 + l4 * 4 + q;
                int cg = j * 64 + wn * 16 + l15;
                pO[((size_t)gm * SPLITS + split) * C_DIM + cg] = of[j][mf][q];
            }
    if (wn == 0 && l15 == 0) {
#pragma unroll
        for (int mf = 0; mf < 2; ++mf)
#pragma unroll
            for (int q = 0; q < 4; ++q) {
                int gm = rb + wm * 32 + mf * 16 + l4 * 4 + q;
                pM[gm * SPLITS + split] = Mr[mf][q];
                pL[gm * SPLITS + split] = Lr[mf][q];
            }
    }
}

// ======================= split-K combine =======================
__global__ void k_combine(const float* __restrict__ pO, const float* __restrict__ pM,
                          const float* __restrict__ pL, const float4* __restrict__ rowp,
                          float* __restrict__ out) {
    int r = blockIdx.x;
    int tid = threadIdx.x;   // 128 threads, 4 c's each
    float ce = rowp[r].z;
    float Ms[SPLITS], Ls[SPLITS];
    float M = -1e30f;
#pragma unroll
    for (int s = 0; s < SPLITS; ++s) {
        Ms[s] = pM[r * SPLITS + s];
        Ls[s] = pL[r * SPLITS + s];
        M = fmaxf(M, Ms[s]);
    }
    float es[SPLITS], L = 0.f;
#pragma unroll
    for (int s = 0; s < SPLITS; ++s) { es[s] = exp2f((Ms[s] - M) * ce); L += Ls[s] * es[s]; }
    float invL = 1.0f / L;
    f32x4 acc = (f32x4){0.f, 0.f, 0.f, 0.f};
#pragma unroll
    for (int s = 0; s < SPLITS; ++s) {
        f32x4 v = *(const f32x4*)(pO + ((size_t)r * SPLITS + s) * C_DIM + tid * 4);
        acc += v * es[s];
    }
    acc *= invL;
    *(f32x4*)(out + (size_t)r * C_DIM + tid * 4) = acc;
}

// ======================= launch =======================
extern "C" void kernel_launch(void* const* d_in, const int* in_sizes, int n_in,
                              void* d_out, int out_size, void* d_ws, size_t ws_size,
                              hipStream_t stream) {
    const float* x = (const float*)d_in[0];
    const int* t = (const int*)d_in[1];
    const float* A = (const float*)d_in[2];
    const float* bar_alpha = (const float*)d_in[3];
    float* out = (float*)d_out;
    char* ws = (char*)d_ws;
    if (ws_size < WS_NEED) return;

    char* imgA = ws + OFF_IMGA;
    char* imgC = ws + OFF_IMGC;
    unsigned short* Xh = (unsigned short*)(ws + OFF_XH);
    unsigned short* Xl = (unsigned short*)(ws + OFF_XL);
    float* Asq = (float*)(ws + OFF_ASQ);
    float4* rowp = (float4*)(ws + OFF_ROWP);
    float* pO = (float*)(ws + OFF_PO);
    float* pM = (float*)(ws + OFF_PM);
    float* pL = (float*)(ws + OFF_PL);

    (void)hipFuncSetAttribute((const void*)k_fused,
                              hipFuncAttributeMaxDynamicSharedMemorySize, SM_TOT);

    k_rows<<<R_DIM / 256, 256, 0, stream>>>(t, bar_alpha, rowp);
    k_splitx<<<(R_DIM * C_DIM / 8) / 256, 256, 0, stream>>>(x, (us8*)Xh, (us8*)Xl);
    k_imgA<<<GTILES * 8, 256, 0, stream>>>(A, imgA);
    k_imgC<<<GTILES * 8, 256, 0, stream>>>(A, imgC);
    k_asq<<<K_DIM / 4, 256, 0, stream>>>(A, Asq);
    k_fused<<<(R_DIM / BM) * SPLITS, 512, SM_TOT, stream>>>(imgA, imgC, Xh, Xl,
                                                            Asq, rowp, pO, pM, pL);
    k_combine<<<R_DIM, 128, 0, stream>>>(pO, pM, pL, rowp, out);
}

// Round 4
// 1051.096 us; speedup vs baseline: 1.1933x; 1.1933x over previous
//
#include <hip/hip_runtime.h>
#include <cstdint>
#include <cstddef>

// Problem constants (R,1,C) x, t, (K,C) A, (T,) bar_alpha
#define R_DIM 4096
#define K_DIM 16384
#define C_DIM 512
#define SPLITS 8                 // split over the 16384 k-dimension
#define BM 128                   // rows per workgroup
#define BK 128                   // k-tile
#define KRANGE (K_DIM / SPLITS)  // 2048
#define NTILES (KRANGE / BK)     // 16
#define GTILES (K_DIM / BK)      // 128 global tiles

typedef unsigned short us8 __attribute__((ext_vector_type(8)));
typedef float f32x4 __attribute__((ext_vector_type(4)));
typedef float f32x16 __attribute__((ext_vector_type(16)));
typedef __bf16 bfv8 __attribute__((ext_vector_type(8)));
typedef _Float16 f16x4 __attribute__((ext_vector_type(4)));

#define MFMA32(a, b, c) __builtin_amdgcn_mfma_f32_32x32x16_bf16((a), (b), (c), 0, 0, 0)
#define BC(v) __builtin_bit_cast(bfv8, (v))

__device__ __forceinline__ unsigned short f2bf(float v) {
    union { float f; unsigned u; } x; x.f = v;
    unsigned r = x.u + 0x7fffu + ((x.u >> 16) & 1u);  // RNE
    return (unsigned short)(r >> 16);
}
__device__ __forceinline__ float bf2f(unsigned short b) {
    union { unsigned u; float f; } x; x.u = ((unsigned)b) << 16;
    return x.f;
}

__device__ __forceinline__ void gload16(const char* g, char* l) {
    __builtin_amdgcn_global_load_lds(
        (const __attribute__((address_space(1))) void*)g,
        (__attribute__((address_space(3))) void*)l, 16, 0, 0);
}

// ---------------- workspace layout (bytes) — total == proven 109,314,048 ----------------
#define OFF_IMGA ((size_t)0)          // [GTILES][8][32768]  32 MB  Phase-A chunk images
#define OFF_IMGC ((size_t)33554432)   // [GTILES][8][32768]  32 MB  Phase-C chunk images
#define OFF_XH   ((size_t)67108864)   // [R][C] bf16 hi    4 MB
#define OFF_XL   ((size_t)71303168)   // [R][C] bf16 lo    4 MB
#define OFF_ASQ  ((size_t)75497472)   // [K] f32          64 KB
#define OFF_PM   ((size_t)75563008)   // [R][SPLITS] f32 128 KB
#define OFF_PL   ((size_t)75694080)   // [R][SPLITS] f16  64 KB
#define OFF_PO   ((size_t)75759616)   // [R][SPLITS][C] f16  32 MB
#define WS_NEED  ((size_t)109314048)

// ---------------- LDS layout (bytes) ----------------
#define SM_BUF0 0        // staging buffer 0: 32 KB (hi 16K, lo 16K)
#define SM_BUF1 32768    // staging buffer 1
#define SM_U    65536    // u hi [128m][128k] bf16 swizzled  32 KB
#define SM_U2   98304    // u lo                             32 KB
#define SM_ROWL 131072   // float2[128] {sa, ce}              1 KB
#define SM_MR   132096   // float[128] running max           512 B
#define SM_LR   132608   // float[128] running sum           512 B
#define SM_MAX  133120   // float[2][128] tile-max exchange    1 KB
#define SM_SUM  134144   // float[2][128] tile-sum exchange    1 KB
#define SM_TOT  135168

// ======================= prep kernels =======================

__global__ void k_splitx(const float* __restrict__ x, us8* __restrict__ xh, us8* __restrict__ xl) {
    int i = blockIdx.x * 256 + threadIdx.x;   // group of 8 elements
    if (i >= R_DIM * C_DIM / 8) return;
    const float4* x4 = (const float4*)x + (size_t)i * 2;
    float v[8];
    float4 a = x4[0], b = x4[1];
    v[0]=a.x; v[1]=a.y; v[2]=a.z; v[3]=a.w; v[4]=b.x; v[5]=b.y; v[6]=b.z; v[7]=b.w;
    us8 h, l;
#pragma unroll
    for (int j = 0; j < 8; ++j) {
        unsigned short hb = f2bf(v[j]);
        h[j] = hb;
        l[j] = f2bf(v[j] - bf2f(hb));
    }
    xh[i] = h; xl[i] = l;
}

// Phase-A chunk images: block=(gt,j). pos = kl*128 + ((cb ^ (kl&7))<<4)
// content: A[gt*128+kl][j*64 + cb*8 .. +8], hi at pos, lo at pos+16384
__global__ __launch_bounds__(256) void k_imgA(const float* __restrict__ A, char* __restrict__ img) {
    int gt = blockIdx.x >> 3, j = blockIdx.x & 7;
    char* base = img + (size_t)blockIdx.x * 32768;
    int t = threadIdx.x;
#pragma unroll
    for (int it = 0; it < 4; ++it) {
        int p = t + it * 256;
        int kl = p >> 3, cb = p & 7;
        const float* src = A + (size_t)(gt * 128 + kl) * C_DIM + j * 64 + cb * 8;
        us8 h, l;
#pragma unroll
        for (int q = 0; q < 8; ++q) {
            float v = src[q];
            unsigned short hb = f2bf(v);
            h[q] = hb; l[q] = f2bf(v - bf2f(hb));
        }
        int pos = kl * 128 + ((cb ^ (kl & 7)) << 4);
        *(us8*)(base + pos) = h;
        *(us8*)(base + 16384 + pos) = l;
    }
}

// Phase-C chunk images (transposed): block=(gt,j). pos = cl*256 + ((kb ^ (cl&7))<<4)
// content: A[gt*128 + kb*8 + q][j*64 + cl], q=0..7
__global__ __launch_bounds__(256) void k_imgC(const float* __restrict__ A, char* __restrict__ img) {
    int gt = blockIdx.x >> 3, j = blockIdx.x & 7;
    char* base = img + (size_t)blockIdx.x * 32768;
    int t = threadIdx.x;
#pragma unroll
    for (int it = 0; it < 4; ++it) {
        int p = t + it * 256;
        int cl = p & 63, kb = p >> 6;
        us8 h, l;
#pragma unroll
        for (int q = 0; q < 8; ++q) {
            float v = A[(size_t)(gt * 128 + kb * 8 + q) * C_DIM + j * 64 + cl];
            unsigned short hb = f2bf(v);
            h[q] = hb; l[q] = f2bf(v - bf2f(hb));
        }
        int pos = cl * 256 + ((kb ^ (cl & 7)) << 4);
        *(us8*)(base + pos) = h;
        *(us8*)(base + 16384 + pos) = l;
    }
}

__global__ void k_asq(const float* __restrict__ A, float* __restrict__ Asq) {
    int wid = threadIdx.x >> 6, lane = threadIdx.x & 63;
    int k = blockIdx.x * 4 + wid;
    const float4* a4 = (const float4*)(A + (size_t)k * C_DIM);
    float s = 0.f;
#pragma unroll
    for (int j = 0; j < 2; ++j) {
        float4 v = a4[lane * 2 + j];
        s += v.x * v.x + v.y * v.y + v.z * v.z + v.w * v.w;
    }
#pragma unroll
    for (int off = 32; off; off >>= 1) s += __shfl_xor(s, off);
    if (lane == 0) Asq[k] = s;
}

// ======================= fused flash-style kernel =======================
// grid = 256: blockIdx = split*32 + rb_idx. XCD = blockIdx%8 = rb_idx%8 ->
// each XCD holds 4 x-slices (1 MB, L2-resident) and streams all img via L3.
// 8 waves = (wm2 = wid>>1: 4 m-quads of 32 rows) x (wk2 = wid&1: k/c halves).
// 32x32x16 MFMA: A row = l&31, k-slot = (l>>5)*8+j; D: col=l&31,
// row=(reg&3)+8*(reg>>2)+4*(l>>5).
__global__ __launch_bounds__(512, 2) void k_fused(
    const char* __restrict__ imgA, const char* __restrict__ imgC,
    const unsigned short* __restrict__ xh, const unsigned short* __restrict__ xl,
    const float* __restrict__ Asq, const int* __restrict__ tarr,
    const float* __restrict__ bar_alpha,
    _Float16* __restrict__ pO, float* __restrict__ pM, _Float16* __restrict__ pL)
{
    extern __shared__ char smem[];
    const int tid = threadIdx.x;
    const int lane = tid & 63, wid = tid >> 6;
    const int wm2 = wid >> 1, wk2 = wid & 1;
    const int l31 = lane & 31, hl = lane >> 5;
    const int split = blockIdx.x >> 5;
    const int rbase = (blockIdx.x & 31) * BM;

    float2* rowl = (float2*)(smem + SM_ROWL);
    float* MrL = (float*)(smem + SM_MR);
    float* LrL = (float*)(smem + SM_LR);
    float* smax = (float*)(smem + SM_MAX);
    float* ssum = (float*)(smem + SM_SUM);

    // prologue: row params + running state
    if (tid < 128) {
        float ba = bar_alpha[tarr[rbase + tid]];
        float sa = sqrtf(ba);
        float ce = 1.4426950408889634f / (1.0f - ba);
        rowl[tid] = make_float2(sa, ce);
        MrL[tid] = -1e30f;
        LrL[tid] = 0.f;
    }
    const int stg = tid * 16;
    {   // stage A(tile0, chunk0) into BUF0
        const char* s = imgA + (size_t)(split * NTILES) * 8 * 32768 + stg;
        char* d = smem + SM_BUF0 + stg;
#pragma unroll
        for (int i = 0; i < 4; ++i) gload16(s + i * 8192, d + i * 8192);
    }
    __syncthreads();
    int cur = 0;

    f32x16 of[8];
#pragma unroll
    for (int j = 0; j < 8; ++j)
#pragma unroll
        for (int r = 0; r < 16; ++r) of[j][r] = 0.f;

    for (int kt = 0; kt < NTILES; ++kt) {
        const int gt = split * NTILES + kt;
        const int kbase = gt * BK;

        f32x16 sf[2];
#pragma unroll
        for (int kq = 0; kq < 2; ++kq)
#pragma unroll
            for (int r = 0; r < 16; ++r) sf[kq][r] = 0.f;

        // ---------- Phase A: S[128m][128k] over c, 8 chunks of 64 ----------
#pragma unroll
        for (int j = 0; j < 8; ++j) {
            {   // stage next chunk (A j+1, or C 0 when j==7)
                const char* s = (j < 7) ? imgA + ((size_t)gt * 8 + j + 1) * 32768
                                        : imgC + ((size_t)gt * 8 + 0) * 32768;
                char* d = smem + (cur ? SM_BUF0 : SM_BUF1) + stg;
#pragma unroll
                for (int i = 0; i < 4; ++i) gload16(s + stg + i * 8192, d + i * 8192);
            }
            const char* B = smem + (cur ? SM_BUF1 : SM_BUF0);
#pragma unroll
            for (int s = 0; s < 4; ++s) {
                int xoff = (rbase + wm2 * 32 + l31) * C_DIM + j * 64 + s * 16 + hl * 8;
                us8 xh8 = *(const us8*)(xh + xoff);
                us8 xl8 = *(const us8*)(xl + xoff);
                int cb = 2 * s + hl;
#pragma unroll
                for (int kq = 0; kq < 2; ++kq) {
                    int kl = wk2 * 64 + kq * 32 + l31;
                    int byte = kl * 128 + ((cb ^ (kl & 7)) << 4);
                    bfv8 qh = *(const bfv8*)(B + byte);
                    bfv8 ql = *(const bfv8*)(B + 16384 + byte);
                    sf[kq] = MFMA32(BC(xh8), qh, sf[kq]);
                    sf[kq] = MFMA32(BC(xh8), ql, sf[kq]);
                    sf[kq] = MFMA32(BC(xl8), qh, sf[kq]);
                }
            }
            __syncthreads();
            cur ^= 1;
        }

        // ---------- Phase B: online softmax ----------
        float asq0 = Asq[kbase + wk2 * 64 + l31];
        float asq1 = Asq[kbase + wk2 * 64 + 32 + l31];
        float mx[16], Mn[16];
#pragma unroll
        for (int i = 0; i < 16; ++i) {
            int ml = wm2 * 32 + (i & 3) + 8 * (i >> 2) + 4 * hl;
            float sa = rowl[ml].x;
            float g0 = sa * (sf[0][i] - 0.5f * sa * asq0);
            float g1 = sa * (sf[1][i] - 0.5f * sa * asq1);
            mx[i] = fmaxf(g0, g1);
        }
#pragma unroll
        for (int off = 1; off < 32; off <<= 1)
#pragma unroll
            for (int i = 0; i < 16; ++i) mx[i] = fmaxf(mx[i], __shfl_xor(mx[i], off));
        if (l31 == 0) {
#pragma unroll
            for (int i = 0; i < 16; ++i)
                smax[wk2 * 128 + wm2 * 32 + (i & 3) + 8 * (i >> 2) + 4 * hl] = mx[i];
        }
        __syncthreads();
        float ts[16];
#pragma unroll
        for (int i = 0; i < 16; ++i) {
            int ml = wm2 * 32 + (i & 3) + 8 * (i >> 2) + 4 * hl;
            Mn[i] = fmaxf(MrL[ml], fmaxf(smax[ml], smax[128 + ml]));
            ts[i] = 0.f;
        }
#pragma unroll
        for (int kq = 0; kq < 2; ++kq) {
            int k = wk2 * 64 + kq * 32 + l31;
            int kb = k >> 3;
            float aq = kq ? asq1 : asq0;
#pragma unroll
            for (int i = 0; i < 16; ++i) {
                int ml = wm2 * 32 + (i & 3) + 8 * (i >> 2) + 4 * hl;
                float2 p = rowl[ml];
                float g = p.x * (sf[kq][i] - 0.5f * p.x * aq);
                float u = exp2f((g - Mn[i]) * p.y);
                ts[i] += u;
                unsigned short uh = f2bf(u);
                unsigned short ul = f2bf(u - bf2f(uh));
                int byte = ml * 256 + ((kb ^ (ml & 7)) << 4) + (k & 7) * 2;
                *(unsigned short*)(smem + SM_U + byte) = uh;
                *(unsigned short*)(smem + SM_U2 + byte) = ul;
            }
        }
#pragma unroll
        for (int off = 1; off < 32; off <<= 1)
#pragma unroll
            for (int i = 0; i < 16; ++i) ts[i] += __shfl_xor(ts[i], off);
        if (l31 == 0) {
#pragma unroll
            for (int i = 0; i < 16; ++i)
                ssum[wk2 * 128 + wm2 * 32 + (i & 3) + 8 * (i >> 2) + 4 * hl] = ts[i];
        }
        __syncthreads();
        // al + of-rescale + u-fragment loads (reads of MrL all before B3)
        float al[16];
#pragma unroll
        for (int i = 0; i < 16; ++i) {
            int ml = wm2 * 32 + (i & 3) + 8 * (i >> 2) + 4 * hl;
            al[i] = exp2f((MrL[ml] - Mn[i]) * rowl[ml].y);
        }
#pragma unroll
        for (int j = 0; j < 8; ++j)
#pragma unroll
            for (int r = 0; r < 16; ++r) of[j][r] *= al[r];
        bfv8 uH[8], uL[8];
#pragma unroll
        for (int ks = 0; ks < 8; ++ks) {
            int m2 = wm2 * 32 + l31;
            int kb = 2 * ks + hl;
            int byte = m2 * 256 + ((kb ^ (m2 & 7)) << 4);
            uH[ks] = *(const bfv8*)(smem + SM_U + byte);
            uL[ks] = *(const bfv8*)(smem + SM_U2 + byte);
        }
        __syncthreads();
        if (wk2 == 0 && l31 == 0) {
#pragma unroll
            for (int i = 0; i < 16; ++i) {
                int ml = wm2 * 32 + (i & 3) + 8 * (i >> 2) + 4 * hl;
                LrL[ml] = LrL[ml] * al[i] + ssum[ml] + ssum[128 + ml];
                MrL[ml] = Mn[i];
            }
        }

        // ---------- Phase C: O[128m][512c] += u * A_tile, 8 chunks of 64 c ----------
#pragma unroll
        for (int j = 0; j < 8; ++j) {
            if (j < 7) {
                const char* s = imgC + ((size_t)gt * 8 + j + 1) * 32768;
                char* d = smem + (cur ? SM_BUF0 : SM_BUF1) + stg;
#pragma unroll
                for (int i = 0; i < 4; ++i) gload16(s + stg + i * 8192, d + i * 8192);
            } else if (kt < NTILES - 1) {
                const char* s = imgA + ((size_t)(gt + 1) * 8 + 0) * 32768;
                char* d = smem + (cur ? SM_BUF0 : SM_BUF1) + stg;
#pragma unroll
                for (int i = 0; i < 4; ++i) gload16(s + stg + i * 8192, d + i * 8192);
            }
            const char* B = smem + (cur ? SM_BUF1 : SM_BUF0);
#pragma unroll
            for (int ks = 0; ks < 8; ++ks) {
                int cl = wk2 * 32 + l31;
                int kb = 2 * ks + hl;
                int byte = cl * 256 + ((kb ^ (cl & 7)) << 4);
                bfv8 qh = *(const bfv8*)(B + byte);
                bfv8 ql = *(const bfv8*)(B + 16384 + byte);
                of[j] = MFMA32(uH[ks], qh, of[j]);
                of[j] = MFMA32(uH[ks], ql, of[j]);
                of[j] = MFMA32(uL[ks], qh, of[j]);
            }
            __syncthreads();
            cur ^= 1;
        }
    }

    // ---------- write split partials ----------
#pragma unroll
    for (int j = 0; j < 8; ++j)
#pragma unroll
        for (int r = 0; r < 16; ++r) {
            int gm = rbase + wm2 * 32 + (r & 3) + 8 * (r >> 2) + 4 * hl;
            int cg = j * 64 + wk2 * 32 + l31;
            pO[((size_t)gm * SPLITS + split) * C_DIM + cg] = (_Float16)of[j][r];
        }
    if (tid < 128) {
        pM[(rbase + tid) * SPLITS + split] = MrL[tid];
        pL[(rbase + tid) * SPLITS + split] = (_Float16)LrL[tid];
    }
}

// ======================= split-K combine =======================
__global__ void k_combine(const _Float16* __restrict__ pO, const float* __restrict__ pM,
                          const _Float16* __restrict__ pL, const int* __restrict__ tarr,
                          const float* __restrict__ bar_alpha, float* __restrict__ out) {
    int r = blockIdx.x;
    int tid = threadIdx.x;   // 128 threads, 4 c's each
    float ba = bar_alpha[tarr[r]];
    float ce = 1.4426950408889634f / (1.0f - ba);
    float Ms[SPLITS], Ls[SPLITS];
    float M = -1e30f;
#pragma unroll
    for (int s = 0; s < SPLITS; ++s) {
        Ms[s] = pM[r * SPLITS + s];
        Ls[s] = (float)pL[r * SPLITS + s];
        M = fmaxf(M, Ms[s]);
    }
    float es[SPLITS], L = 0.f;
#pragma unroll
    for (int s = 0; s < SPLITS; ++s) { es[s] = exp2f((Ms[s] - M) * ce); L += Ls[s] * es[s]; }
    float invL = 1.0f / L;
    f32x4 acc = (f32x4){0.f, 0.f, 0.f, 0.f};
#pragma unroll
    for (int s = 0; s < SPLITS; ++s) {
        f16x4 v = *(const f16x4*)(pO + ((size_t)r * SPLITS + s) * C_DIM + tid * 4);
        f32x4 vf = (f32x4){(float)v[0], (float)v[1], (float)v[2], (float)v[3]};
        acc += vf * es[s];
    }
    acc *= invL;
    *(f32x4*)(out + (size_t)r * C_DIM + tid * 4) = acc;
}

// ======================= launch =======================
extern "C" void kernel_launch(void* const* d_in, const int* in_sizes, int n_in,
                              void* d_out, int out_size, void* d_ws, size_t ws_size,
                              hipStream_t stream) {
    const float* x = (const float*)d_in[0];
    const int* t = (const int*)d_in[1];
    const float* A = (const float*)d_in[2];
    const float* bar_alpha = (const float*)d_in[3];
    float* out = (float*)d_out;
    char* ws = (char*)d_ws;
    if (ws_size < WS_NEED) return;

    char* imgA = ws + OFF_IMGA;
    char* imgC = ws + OFF_IMGC;
    unsigned short* Xh = (unsigned short*)(ws + OFF_XH);
    unsigned short* Xl = (unsigned short*)(ws + OFF_XL);
    float* Asq = (float*)(ws + OFF_ASQ);
    float* pM = (float*)(ws + OFF_PM);
    _Float16* pL = (_Float16*)(ws + OFF_PL);
    _Float16* pO = (_Float16*)(ws + OFF_PO);

    (void)hipFuncSetAttribute((const void*)k_fused,
                              hipFuncAttributeMaxDynamicSharedMemorySize, SM_TOT);

    k_splitx<<<(R_DIM * C_DIM / 8) / 256, 256, 0, stream>>>(x, (us8*)Xh, (us8*)Xl);
    k_imgA<<<GTILES * 8, 256, 0, stream>>>(A, imgA);
    k_imgC<<<GTILES * 8, 256, 0, stream>>>(A, imgC);
    k_asq<<<K_DIM / 4, 256, 0, stream>>>(A, Asq);
    k_fused<<<256, 512, SM_TOT, stream>>>(imgA, imgC, Xh, Xl, Asq, t, bar_alpha,
                                          pO, pM, pL);
    k_combine<<<R_DIM, 128, 0, stream>>>(pO, pM, pL, t, bar_alpha, out);
}